// Round 1
// baseline (10111.777 us; speedup 1.0000x reference)
//
#include <hip/hip_runtime.h>

typedef _Float16 f16;
typedef _Float16 f16x8 __attribute__((ext_vector_type(8)));
typedef float f32x4 __attribute__((ext_vector_type(4)));
typedef unsigned long long u64;

constexpr int NB = 8;        // batch
constexpr int SEQ = 512;     // seq len
constexpr int ED = 512;      // embed dim
constexpr int HD = 512;      // hidden
constexpr int NROWS = NB * SEQ;   // 4096
constexpr int GD = 4 * HD;        // 2048 gate cols

__device__ __forceinline__ float wred_sum(float v) {
    #pragma unroll
    for (int off = 32; off > 0; off >>= 1) v += __shfl_xor(v, off, 64);
    return v;
}
__device__ __forceinline__ float wred_max(float v) {
    #pragma unroll
    for (int off = 32; off > 0; off >>= 1) v = fmaxf(v, __shfl_xor(v, off, 64));
    return v;
}

// ---------------- generic f16-MFMA GEMM: C = A(f32,MxK) @ B + bias ----------
// BT=0: B is row-major KxN (ldb = row stride). BT=1: B is row-major NxK.
// 128x128 tile per 256-thread block; wave computes 64x64 via 4x4 mfma_16x16x32.
template<int BT>
__global__ __launch_bounds__(256)
void gemm_f16(const float* __restrict__ A, int lda, long long strideA,
              const float* __restrict__ Bm, int ldb, long long strideB,
              const float* __restrict__ bias,
              float* __restrict__ C, int ldc, long long strideC, int K)
{
    __shared__ f16 As[128][40];   // pad 40 to break bank conflicts
    __shared__ f16 Bs[128][40];   // stored as [n][k]
    A  += (size_t)blockIdx.z * strideA;
    Bm += (size_t)blockIdx.z * strideB;
    C  += (size_t)blockIdx.z * strideC;
    const int tid = threadIdx.x;
    const int gM = blockIdx.y * 128;
    const int gN = blockIdx.x * 128;
    const int wave = tid >> 6, lane = tid & 63;
    const int wm = (wave >> 1) * 64, wn = (wave & 1) * 64;
    const int fl = lane & 15, fq = lane >> 4;
    f32x4 acc[4][4];
    #pragma unroll
    for (int i = 0; i < 4; i++)
        #pragma unroll
        for (int j = 0; j < 4; j++) acc[i][j] = (f32x4){0.f, 0.f, 0.f, 0.f};

    const int arow = tid >> 1;
    const int akg  = (tid & 1) * 16;
    const int bn   = tid & 127;
    const int bkg  = (tid >> 7) * 16;

    for (int k0 = 0; k0 < K; k0 += 32) {
        __syncthreads();
        {   // stage A tile 128x32 (fp32 -> f16)
            const float* src = A + (size_t)(gM + arow) * lda + k0 + akg;
            f16* dst = &As[arow][akg];
            #pragma unroll
            for (int u = 0; u < 16; u += 4) {
                float4 v = *(const float4*)(src + u);
                dst[u+0]=(f16)v.x; dst[u+1]=(f16)v.y; dst[u+2]=(f16)v.z; dst[u+3]=(f16)v.w;
            }
        }
        if (BT) {
            const float* src = Bm + (size_t)(gN + arow) * ldb + k0 + akg;
            f16* dst = &Bs[arow][akg];
            #pragma unroll
            for (int u = 0; u < 16; u += 4) {
                float4 v = *(const float4*)(src + u);
                dst[u+0]=(f16)v.x; dst[u+1]=(f16)v.y; dst[u+2]=(f16)v.z; dst[u+3]=(f16)v.w;
            }
        } else {
            const float* src = Bm + (size_t)(k0 + bkg) * ldb + gN + bn;
            #pragma unroll
            for (int u = 0; u < 16; u++)
                Bs[bn][bkg + u] = (f16)src[(size_t)u * ldb];
        }
        __syncthreads();
        f16x8 af[4], bf[4];
        #pragma unroll
        for (int i = 0; i < 4; i++) af[i] = *(const f16x8*)&As[wm + 16*i + fl][fq*8];
        #pragma unroll
        for (int j = 0; j < 4; j++) bf[j] = *(const f16x8*)&Bs[wn + 16*j + fl][fq*8];
        #pragma unroll
        for (int i = 0; i < 4; i++)
            #pragma unroll
            for (int j = 0; j < 4; j++)
                acc[i][j] = __builtin_amdgcn_mfma_f32_16x16x32_f16(af[i], bf[j], acc[i][j], 0, 0, 0);
    }
    #pragma unroll
    for (int j = 0; j < 4; j++) {
        const int col = gN + wn + 16*j + fl;
        const float bv = bias ? bias[col] : 0.f;
        #pragma unroll
        for (int i = 0; i < 4; i++) {
            const int row0 = gM + wm + 16*i + fq*4;
            #pragma unroll
            for (int r = 0; r < 4; r++)
                C[(size_t)(row0 + r) * ldc + col] = acc[i][j][r] + bv;
        }
    }
}

// ---------------- persistent BiLSTM layer --------------------------------
// 128 blocks x 128 threads: blocks [0,64) forward, [64,128) backward.
// Each WG owns 8 hidden units (32 gate cols); its W-slice (512x32) lives in
// LDS as f16. The recurrent h vector is exchanged between WGs as PACKED
// f16x4 u64 RELAXED agent-scope atomics (write-through to the coherence
// point, loads bypass stale per-XCD L2) -> no buffer_inv/wbl2-heavy
// acquire fences on the critical path. One slot per WAVE (128/dir); the
// slot store is RELEASE (its vmcnt(0) orders the preceding h stores).
// Readers gather A-fragments for mfma_16x16x32 straight into registers
// (lane fl<8 = batch row), so the step loop has ZERO __syncthreads().
// Gate columns are remapped so lc -> (gate=(lc>>2)&3, j=(lc&3)+4*(lc>>4)):
// the 4 gate values of one (b,j) land in a 4-lane quad of one wave and are
// combined with 3 shfl_xor ops; c/h state lives in registers of the fl<4
// "owner" lanes. tanh(x) = 2*sigmoid(2x)-1 (single expf, branch-free).
constexpr int LWG = 64;          // WGs per direction
constexpr int JW = HD / LWG;     // 8 hidden units per WG
constexpr int LK = 520;          // padded LDS k-stride (f16 elems)

__global__ __launch_bounds__(128)
void lstm_layer(const float* __restrict__ xgf, const float* __restrict__ xgb,
                const float* __restrict__ Wfull_f, const float* __restrict__ Wfull_b, int rowOff,
                const float* __restrict__ h0f, const float* __restrict__ c0f,
                const float* __restrict__ h0b, const float* __restrict__ c0b,
                const int* __restrict__ xtok,
                float* __restrict__ outbuf,       // [4096][1024], cols dir*512 + j
                u64* __restrict__ hbuf,           // [2 dirs][2 phases][8 b][128] f16x4
                unsigned int* __restrict__ slots) // [2 dirs][128] one per wave
{
    __shared__ f16 Ws[32 * LK];   // [local col][k]

    const int bid = blockIdx.x;
    const int dir = bid >> 6;
    const int wg  = bid & 63;
    const int j0  = wg * JW;
    const int tid = threadIdx.x;
    const float* xg = dir ? xgb : xgf;
    const float* Wr = (dir ? Wfull_b : Wfull_f) + (size_t)rowOff * GD;  // h-part rows
    const float* h0 = dir ? h0b : h0f;
    const float* c0 = dir ? c0b : c0f;
    u64* hb = hbuf + dir * 2048;
    unsigned int* slot = slots + dir * 128;

    const int lane = tid & 63;
    const int wv   = tid >> 6;           // wave -> n-subtile (j 0..3 / 4..7)
    const int fl   = lane & 15;
    const int fq   = lane >> 4;
    const int gate = fl >> 2;            // 0=i 1=f 2=o 3=g
    const int jown = (fl & 3) + 4 * wv;  // 0..7
    const int gcol = gate * HD + j0 + jown;
    const bool owner = (fl < 4) && (fq < 2);
    const int srcBase = lane & 48;       // fq*16 (quad base for pack shfl)

    // ---- init c/h state in registers, publish h(0), raise slot ----
    float creg[4], hreg[4];
    {
        const float cv = owner ? c0[j0 + jown] : 0.f;
        const float hv = owner ? h0[j0 + jown] : 0.f;
        #pragma unroll
        for (int r = 0; r < 4; r++) { creg[r] = cv; hreg[r] = hv; }
        #pragma unroll
        for (int r = 0; r < 4; r++) {
            const float b0 = __shfl(hreg[r], srcBase | 0, 64);
            const float b1 = __shfl(hreg[r], srcBase | 1, 64);
            const float b2 = __shfl(hreg[r], srcBase | 2, 64);
            const float b3 = __shfl(hreg[r], srcBase | 3, 64);
            if (fl == 0 && fq < 2) {
                union { u64 u; f16 h[4]; } p;
                p.h[0]=(f16)b0; p.h[1]=(f16)b1; p.h[2]=(f16)b2; p.h[3]=(f16)b3;
                __hip_atomic_store(&hb[(fq*4 + r) * 128 + (j0 >> 2) + wv], p.u,
                                   __ATOMIC_RELAXED, __HIP_MEMORY_SCOPE_AGENT);
            }
        }
        if (lane == 0)
            __hip_atomic_store(&slot[wg * 2 + wv], 1u,
                               __ATOMIC_RELEASE, __HIP_MEMORY_SCOPE_AGENT);
    }

    // ---- preload W slice into LDS (remapped local columns), once ----
    for (int idx = tid; idx < 32 * 512; idx += 128) {
        const int k  = idx >> 5;
        const int lc = idx & 31;
        const int g  = (lc >> 2) & 3;
        const int jj = (lc & 3) + 4 * (lc >> 4);
        Ws[lc * LK + k] = (f16)Wr[(size_t)k * GD + g * HD + j0 + jj];
    }
    __syncthreads();   // only block barrier in the kernel

    for (int s = 0; s < SEQ; s++) {
        const int t = dir ? (SEQ - 1 - s) : s;

        // prefetch x-gate contributions + tokens (independent of h; overlaps spin)
        float xgv[4];
        if (fq < 2) {
            #pragma unroll
            for (int r = 0; r < 4; r++)
                xgv[r] = xg[(size_t)((fq*4 + r) * SEQ + t) * GD + gcol];
        }
        int tok[4] = {0, 0, 0, 0};
        if (owner) {
            #pragma unroll
            for (int r = 0; r < 4; r++) tok[r] = xtok[(fq*4 + r) * SEQ + t];
        }

        // wait for everyone's h(s): relaxed polls, no cache-maintenance ops
        const unsigned target = (unsigned)(s + 1);
        while (true) {
            const unsigned va = __hip_atomic_load(&slot[lane],      __ATOMIC_RELAXED, __HIP_MEMORY_SCOPE_AGENT);
            const unsigned vb = __hip_atomic_load(&slot[64 + lane], __ATOMIC_RELAXED, __HIP_MEMORY_SCOPE_AGENT);
            if (__all((va >= target) & (vb >= target))) break;
            __builtin_amdgcn_s_sleep(1);
        }
        asm volatile("" ::: "memory");

        // gather h(s) A-fragments straight into registers (lane fl = batch row)
        u64 q0[16], q1[16];
        if (fl < 8) {
            const u64* p = hb + (s & 1) * 1024 + fl * 128 + fq * 2;
            #pragma unroll
            for (int kc = 0; kc < 16; kc++) {
                q0[kc] = __hip_atomic_load(&p[kc*8 + 0], __ATOMIC_RELAXED, __HIP_MEMORY_SCOPE_AGENT);
                q1[kc] = __hip_atomic_load(&p[kc*8 + 1], __ATOMIC_RELAXED, __HIP_MEMORY_SCOPE_AGENT);
            }
        } else {
            #pragma unroll
            for (int kc = 0; kc < 16; kc++) { q0[kc] = 0; q1[kc] = 0; }
        }

        // recurrent matmul S = h @ Wslice, two accumulator chains
        f32x4 acc0 = {0.f,0.f,0.f,0.f}, acc1 = {0.f,0.f,0.f,0.f};
        #pragma unroll
        for (int kc = 0; kc < 16; kc += 2) {
            union { u64 qq[2]; f16x8 v; } a0, a1;
            a0.qq[0] = q0[kc];     a0.qq[1] = q1[kc];
            a1.qq[0] = q0[kc + 1]; a1.qq[1] = q1[kc + 1];
            const f16x8 b0 = *(const f16x8*)&Ws[(wv*16 + fl) * LK + (kc    )*32 + fq*8];
            const f16x8 b1 = *(const f16x8*)&Ws[(wv*16 + fl) * LK + (kc + 1)*32 + fq*8];
            acc0 = __builtin_amdgcn_mfma_f32_16x16x32_f16(a0.v, b0, acc0, 0, 0, 0);
            acc1 = __builtin_amdgcn_mfma_f32_16x16x32_f16(a1.v, b1, acc1, 0, 0, 0);
        }

        // nonlinearity: gates 0..2 sigmoid, gate 3 tanh = 2*sig(2x)-1
        const bool isg = (gate == 3);
        float nl[4];
        #pragma unroll
        for (int r = 0; r < 4; r++) {
            float v = acc0[r] + acc1[r];
            if (fq < 2) v += xgv[r];
            const float a2 = isg ? (v + v) : v;
            const float sg = 1.f / (1.f + expf(-a2));
            nl[r] = isg ? (sg + sg - 1.f) : sg;
        }

        // butterfly across the gate dimension (quad lanes fl, fl^4, fl^8, fl^12)
        float outv[4];
        #pragma unroll
        for (int r = 0; r < 4; r++) {
            const float P = nl[r];
            const float Q = __shfl_xor(P, 4, 64);
            const float U = (gate & 1) ? Q : P;     // i (gates 0/1) or o (2/3)
            const float V = (gate & 1) ? P : Q;     // f or g
            const float U8 = __shfl_xor(U, 8, 64);
            const float V8 = __shfl_xor(V, 8, 64);
            const bool hi = (gate >= 2);
            const float gi = hi ? U8 : U;
            const float gf = hi ? V8 : V;
            const float go = hi ? U  : U8;
            const float gg = hi ? V  : V8;
            const float cn = gf * creg[r] + gi * gg;
            const float hn = go * tanhf(cn);
            const bool act = owner && (tok[r] != 0);
            creg[r] = act ? cn : creg[r];
            hreg[r] = act ? hn : hreg[r];
            outv[r] = act ? hn : 0.f;
        }

        // publish h(s+1): pack f16x4 per batch, then RELEASE the wave slot
        u64* dst = hb + ((s + 1) & 1) * 1024;
        #pragma unroll
        for (int r = 0; r < 4; r++) {
            const float b0 = __shfl(hreg[r], srcBase | 0, 64);
            const float b1 = __shfl(hreg[r], srcBase | 1, 64);
            const float b2 = __shfl(hreg[r], srcBase | 2, 64);
            const float b3 = __shfl(hreg[r], srcBase | 3, 64);
            if (fl == 0 && fq < 2) {
                union { u64 u; f16 h[4]; } p;
                p.h[0]=(f16)b0; p.h[1]=(f16)b1; p.h[2]=(f16)b2; p.h[3]=(f16)b3;
                __hip_atomic_store(&dst[(fq*4 + r) * 128 + (j0 >> 2) + wv], p.u,
                                   __ATOMIC_RELAXED, __HIP_MEMORY_SCOPE_AGENT);
            }
        }
        if (lane == 0)
            __hip_atomic_store(&slot[wg * 2 + wv], (unsigned)(s + 2),
                               __ATOMIC_RELEASE, __HIP_MEMORY_SCOPE_AGENT);

        // sequence output (off the critical path, flushed at kernel end)
        if (owner) {
            #pragma unroll
            for (int r = 0; r < 4; r++)
                outbuf[(size_t)((fq*4 + r) * SEQ + t) * 1024 + dir * 512 + j0 + jown] = outv[r];
        }
    }
}

// ---------------- small kernels ------------------------------------------
__global__ void init_slots(unsigned int* s) { s[threadIdx.x] = 0u; }

__global__ __launch_bounds__(128)
void embed_kernel(const int* __restrict__ xtok, const float* __restrict__ emb,
                  float* __restrict__ dst) {
    const int r = blockIdx.x;
    const int tok = xtok[r];
    const float4* src = (const float4*)(emb + (size_t)tok * ED);
    float4* d = (float4*)(dst + (size_t)r * ED);
    d[threadIdx.x] = src[threadIdx.x];
}

__global__ __launch_bounds__(256)
void copycat_kernel(const float* __restrict__ enc, float* __restrict__ cat) {
    const int r = blockIdx.x;
    const int i = threadIdx.x * 4;
    *(float4*)&cat[(size_t)r * 2048 + i] = *(const float4*)&enc[(size_t)r * 1024 + i];
}

__global__ __launch_bounds__(256)
void softmax_kernel(float* __restrict__ sc, const int* __restrict__ xtok) {
    __shared__ float sm[4];
    const int r = blockIdx.x;          // b*512 + q
    const int b = r >> 9;
    const bool validq = xtok[r] != 0;
    float* row = sc + (size_t)r * 512;
    const int tid = threadIdx.x;
    float v0 = row[tid] * 0.03125f;
    float v1 = row[tid + 256] * 0.03125f;
    v0 = (xtok[(b << 9) + tid]       != 0) ? v0 : -3.402823466e38f;
    v1 = (xtok[(b << 9) + tid + 256] != 0) ? v1 : -3.402823466e38f;
    if (!validq) { v0 = 0.f; v1 = 0.f; }
    float m = wred_max(fmaxf(v0, v1));
    if ((tid & 63) == 0) sm[tid >> 6] = m;
    __syncthreads();
    m = fmaxf(fmaxf(sm[0], sm[1]), fmaxf(sm[2], sm[3]));
    const float e0 = expf(v0 - m), e1 = expf(v1 - m);
    float ssum = wred_sum(e0 + e1);
    __syncthreads();
    if ((tid & 63) == 0) sm[tid >> 6] = ssum;
    __syncthreads();
    ssum = (sm[0] + sm[1]) + (sm[2] + sm[3]);
    const float inv = 1.f / ssum;
    row[tid]       = validq ? e0 * inv : 0.f;
    row[tid + 256] = validq ? e1 * inv : 0.f;
}

__global__ __launch_bounds__(256)
void ln1_kernel(const float* __restrict__ enc, const float* __restrict__ ao,
                const float* __restrict__ g, const float* __restrict__ be,
                const int* __restrict__ xtok, float* __restrict__ out) {
    __shared__ float sm[8];
    const int r = blockIdx.x;
    const bool valid = xtok[r] != 0;
    const float* er = enc + (size_t)r * 1024;
    const float* ar = ao + (size_t)r * 1024;
    float* orow = out + (size_t)r * 1024;
    const int tid = threadIdx.x;
    float v[4]; float s = 0.f, ss = 0.f;
    #pragma unroll
    for (int u = 0; u < 4; u++) {
        const int d = tid + u * 256;
        const float val = er[d] + tanhf(ar[d]);
        v[u] = val; s += val; ss += val * val;
    }
    s = wred_sum(s); ss = wred_sum(ss);
    if ((tid & 63) == 0) { sm[tid >> 6] = s; sm[4 + (tid >> 6)] = ss; }
    __syncthreads();
    s  = (sm[0] + sm[1]) + (sm[2] + sm[3]);
    ss = (sm[4] + sm[5]) + (sm[6] + sm[7]);
    const float mean = s * (1.f / 1024.f);
    const float var = ss * (1.f / 1024.f) - mean * mean;
    const float rstd = rsqrtf(var + 1e-5f);
    #pragma unroll
    for (int u = 0; u < 4; u++) {
        const int d = tid + u * 256;
        const float y = (v[u] - mean) * rstd * g[d] + be[d];
        orow[d] = valid ? y : 0.f;
    }
}

__global__ __launch_bounds__(256)
void ln2_kernel(const float* __restrict__ hp, const float* __restrict__ g,
                const float* __restrict__ be, float* __restrict__ out) {
    __shared__ float sm[8];
    const int r = blockIdx.x;
    const float* src = hp + (size_t)r * 512;
    float* orow = out + (size_t)r * 512;
    const int tid = threadIdx.x;
    float v[2]; float s = 0.f, ss = 0.f;
    #pragma unroll
    for (int u = 0; u < 2; u++) {
        const int d = tid + u * 256;
        const float xx = src[d];
        const float val = 0.5f * xx * (1.f + erff(xx * 0.7071067811865475f)); // exact gelu
        v[u] = val; s += val; ss += val * val;
    }
    s = wred_sum(s); ss = wred_sum(ss);
    if ((tid & 63) == 0) { sm[tid >> 6] = s; sm[4 + (tid >> 6)] = ss; }
    __syncthreads();
    s  = (sm[0] + sm[1]) + (sm[2] + sm[3]);
    ss = (sm[4] + sm[5]) + (sm[6] + sm[7]);
    const float mean = s * (1.f / 512.f);
    const float var = ss * (1.f / 512.f) - mean * mean;
    const float rstd = rsqrtf(var + 1e-5f);
    #pragma unroll
    for (int u = 0; u < 2; u++) {
        const int d = tid + u * 256;
        orow[d] = (v[u] - mean) * rstd * g[d] + be[d];
    }
}

// ---------------- host launcher ------------------------------------------
extern "C" void kernel_launch(void* const* d_in, const int* in_sizes, int n_in,
                              void* d_out, int out_size, void* d_ws, size_t ws_size,
                              hipStream_t stream) {
    const int*   x    = (const int*)  d_in[0];
    const float* emb  = (const float*)d_in[1];
    const float* Wf0  = (const float*)d_in[2];
    const float* bf0  = (const float*)d_in[3];
    const float* Wb0  = (const float*)d_in[4];
    const float* bb0  = (const float*)d_in[5];
    const float* Wf1  = (const float*)d_in[6];
    const float* bf1  = (const float*)d_in[7];
    const float* Wb1  = (const float*)d_in[8];
    const float* bb1  = (const float*)d_in[9];
    const float* h0f  = (const float*)d_in[10];
    const float* c0f  = (const float*)d_in[11];
    const float* h0b  = (const float*)d_in[12];
    const float* c0b  = (const float*)d_in[13];
    const float* Wq   = (const float*)d_in[14];
    const float* bq   = (const float*)d_in[15];
    const float* Wao  = (const float*)d_in[16];
    const float* bao  = (const float*)d_in[17];
    const float* ln1g = (const float*)d_in[18];
    const float* ln1b = (const float*)d_in[19];
    const float* Wh   = (const float*)d_in[20];
    const float* bh   = (const float*)d_in[21];
    const float* ln2g = (const float*)d_in[22];
    const float* ln2b = (const float*)d_in[23];
    const float* Wp   = (const float*)d_in[24];
    const float* obia = (const float*)d_in[25];
    float* out = (float*)d_out;
    float* ws  = (float*)d_ws;

    // Arena inside d_out (524 MB; intermediates ~200 MB, fully overwritten by
    // the final GEMM which only reads head (in d_ws) + Wp + out_bias).
    float* emb_seq = out;                                  // 2M floats
    float* xgf  = out + (size_t)2 * 1024 * 1024;           // 8M (reused layer0/1)
    float* xgb  = xgf + (size_t)8 * 1024 * 1024;           // 8M
    float* lin1 = xgb + (size_t)8 * 1024 * 1024;           // 4M
    float* enc  = lin1 + (size_t)4 * 1024 * 1024;          // 4M
    float* qry  = enc  + (size_t)4 * 1024 * 1024;          // 4M
    float* att  = qry  + (size_t)4 * 1024 * 1024;          // 2M
    float* cat  = att  + (size_t)2 * 1024 * 1024;          // 8M
    float* aop  = cat  + (size_t)8 * 1024 * 1024;          // 4M
    float* refd = aop  + (size_t)4 * 1024 * 1024;          // 4M
    float* hpre = refd + (size_t)4 * 1024 * 1024;          // 2M -> 50M total

    float* head = ws;                                      // 2M floats
    u64*   hbuf = (u64*)(ws + (size_t)2 * 1024 * 1024);    // 4096 u64 = 32 KB
    unsigned int* slots = (unsigned int*)(hbuf + 4096);    // 512 uints (2 layers)

    init_slots<<<1, 512, 0, stream>>>(slots);
    embed_kernel<<<NROWS, 128, 0, stream>>>(x, emb, emb_seq);
    // layer 0 x-gates (bias fused)
    gemm_f16<0><<<dim3(GD/128, NROWS/128, 1), 256, 0, stream>>>(emb_seq, ED, 0, Wf0, GD, 0, bf0, xgf, GD, 0, ED);
    gemm_f16<0><<<dim3(GD/128, NROWS/128, 1), 256, 0, stream>>>(emb_seq, ED, 0, Wb0, GD, 0, bb0, xgb, GD, 0, ED);
    lstm_layer<<<128, 128, 0, stream>>>(xgf, xgb, Wf0, Wb0, ED, h0f, c0f, h0b, c0b, x, lin1, hbuf, slots);
    // layer 1 x-gates (K = 2H = 1024)
    gemm_f16<0><<<dim3(GD/128, NROWS/128, 1), 256, 0, stream>>>(lin1, 1024, 0, Wf1, GD, 0, bf1, xgf, GD, 0, 1024);
    gemm_f16<0><<<dim3(GD/128, NROWS/128, 1), 256, 0, stream>>>(lin1, 1024, 0, Wb1, GD, 0, bb1, xgb, GD, 0, 1024);
    lstm_layer<<<128, 128, 0, stream>>>(xgf, xgb, Wf1, Wb1, 1024, h0f + 512, c0f + 512, h0b + 512, c0b + 512, x, enc, hbuf, slots + 256);
    // attention
    gemm_f16<0><<<dim3(1024/128, NROWS/128, 1), 256, 0, stream>>>(enc, 1024, 0, Wq, 1024, 0, bq, qry, 1024, 0, 1024);
    gemm_f16<1><<<dim3(4, 4, 8), 256, 0, stream>>>(qry, 1024, (long long)512*1024, enc, 1024, (long long)512*1024, nullptr, att, 512, (long long)512*512, 1024);
    softmax_kernel<<<NROWS, 256, 0, stream>>>(att, x);
    copycat_kernel<<<NROWS, 256, 0, stream>>>(enc, cat);
    gemm_f16<0><<<dim3(8, 4, 8), 256, 0, stream>>>(att, 512, (long long)512*512, enc, 1024, (long long)512*1024, nullptr, cat + 1024, 2048, (long long)512*2048, 512);
    // refine + LN1
    gemm_f16<0><<<dim3(1024/128, NROWS/128, 1), 256, 0, stream>>>(cat, 2048, 0, Wao, 1024, 0, bao, aop, 1024, 0, 2048);
    ln1_kernel<<<NROWS, 256, 0, stream>>>(enc, aop, ln1g, ln1b, x, refd);
    // head + LN2
    gemm_f16<0><<<dim3(512/128, NROWS/128, 1), 256, 0, stream>>>(refd, 1024, 0, Wh, 512, 0, bh, hpre, 512, 0, 1024);
    ln2_kernel<<<NROWS, 256, 0, stream>>>(hpre, ln2g, ln2b, head);
    // vocab projection (writes every element of d_out)
    gemm_f16<0><<<dim3(32000/128, NROWS/128, 1), 256, 0, stream>>>(head, 512, 0, Wp, 32000, 0, obia, out, 32000, 0, 512);
}

// Round 2
// 6345.148 us; speedup vs baseline: 1.5936x; 1.5936x over previous
//
#include <hip/hip_runtime.h>

typedef _Float16 f16;
typedef _Float16 f16x8 __attribute__((ext_vector_type(8)));
typedef float f32x4 __attribute__((ext_vector_type(4)));
typedef unsigned long long u64;

constexpr int NB = 8;        // batch
constexpr int SEQ = 512;     // seq len
constexpr int ED = 512;      // embed dim
constexpr int HD = 512;      // hidden
constexpr int NROWS = NB * SEQ;   // 4096
constexpr int GD = 4 * HD;        // 2048 gate cols

__device__ __forceinline__ float wred_sum(float v) {
    #pragma unroll
    for (int off = 32; off > 0; off >>= 1) v += __shfl_xor(v, off, 64);
    return v;
}
__device__ __forceinline__ float wred_max(float v) {
    #pragma unroll
    for (int off = 32; off > 0; off >>= 1) v = fmaxf(v, __shfl_xor(v, off, 64));
    return v;
}

// ---------------- generic f16-MFMA GEMM: C = A(f32,MxK) @ B + bias ----------
// BT=0: B is row-major KxN (ldb = row stride). BT=1: B is row-major NxK.
// 128x128 tile per 256-thread block; wave computes 64x64 via 4x4 mfma_16x16x32.
template<int BT>
__global__ __launch_bounds__(256)
void gemm_f16(const float* __restrict__ A, int lda, long long strideA,
              const float* __restrict__ Bm, int ldb, long long strideB,
              const float* __restrict__ bias,
              float* __restrict__ C, int ldc, long long strideC, int K)
{
    __shared__ f16 As[128][40];   // pad 40 to break bank conflicts
    __shared__ f16 Bs[128][40];   // stored as [n][k]
    A  += (size_t)blockIdx.z * strideA;
    Bm += (size_t)blockIdx.z * strideB;
    C  += (size_t)blockIdx.z * strideC;
    const int tid = threadIdx.x;
    const int gM = blockIdx.y * 128;
    const int gN = blockIdx.x * 128;
    const int wave = tid >> 6, lane = tid & 63;
    const int wm = (wave >> 1) * 64, wn = (wave & 1) * 64;
    const int fl = lane & 15, fq = lane >> 4;
    f32x4 acc[4][4];
    #pragma unroll
    for (int i = 0; i < 4; i++)
        #pragma unroll
        for (int j = 0; j < 4; j++) acc[i][j] = (f32x4){0.f, 0.f, 0.f, 0.f};

    const int arow = tid >> 1;
    const int akg  = (tid & 1) * 16;
    const int bn   = tid & 127;
    const int bkg  = (tid >> 7) * 16;

    for (int k0 = 0; k0 < K; k0 += 32) {
        __syncthreads();
        {   // stage A tile 128x32 (fp32 -> f16)
            const float* src = A + (size_t)(gM + arow) * lda + k0 + akg;
            f16* dst = &As[arow][akg];
            #pragma unroll
            for (int u = 0; u < 16; u += 4) {
                float4 v = *(const float4*)(src + u);
                dst[u+0]=(f16)v.x; dst[u+1]=(f16)v.y; dst[u+2]=(f16)v.z; dst[u+3]=(f16)v.w;
            }
        }
        if (BT) {
            const float* src = Bm + (size_t)(gN + arow) * ldb + k0 + akg;
            f16* dst = &Bs[arow][akg];
            #pragma unroll
            for (int u = 0; u < 16; u += 4) {
                float4 v = *(const float4*)(src + u);
                dst[u+0]=(f16)v.x; dst[u+1]=(f16)v.y; dst[u+2]=(f16)v.z; dst[u+3]=(f16)v.w;
            }
        } else {
            const float* src = Bm + (size_t)(k0 + bkg) * ldb + gN + bn;
            #pragma unroll
            for (int u = 0; u < 16; u++)
                Bs[bn][bkg + u] = (f16)src[(size_t)u * ldb];
        }
        __syncthreads();
        f16x8 af[4], bf[4];
        #pragma unroll
        for (int i = 0; i < 4; i++) af[i] = *(const f16x8*)&As[wm + 16*i + fl][fq*8];
        #pragma unroll
        for (int j = 0; j < 4; j++) bf[j] = *(const f16x8*)&Bs[wn + 16*j + fl][fq*8];
        #pragma unroll
        for (int i = 0; i < 4; i++)
            #pragma unroll
            for (int j = 0; j < 4; j++)
                acc[i][j] = __builtin_amdgcn_mfma_f32_16x16x32_f16(af[i], bf[j], acc[i][j], 0, 0, 0);
    }
    #pragma unroll
    for (int j = 0; j < 4; j++) {
        const int col = gN + wn + 16*j + fl;
        const float bv = bias ? bias[col] : 0.f;
        #pragma unroll
        for (int i = 0; i < 4; i++) {
            const int row0 = gM + wm + 16*i + fq*4;
            #pragma unroll
            for (int r = 0; r < 4; r++)
                C[(size_t)(row0 + r) * ldc + col] = acc[i][j][r] + bv;
        }
    }
}

// ---------------- persistent BiLSTM layer --------------------------------
// 32 blocks x 512 threads: blocks [0,16) forward, [16,32) backward.
// Each WG owns 32 hidden units (128 gate cols); its W-slice (512x128) lives
// in LDS as f16 (128 KB, k-major). Recurrent h is exchanged via the LLC as
// packed f16x4 u64 RELAXED agent-scope atomics with layout [jb][batch] so
// both the publish (one 64B line per wave) and the cooperative gather
// (2 contiguous u64 per thread, 16 coalesced wave-instrs for all 8 KB) are
// line-friendly. Gather stages into LDS in MFMA A-frag layout; 16 MFMA per
// wave per step. Sync: ONE slot per WG (16/dir, single cache line); only
// wave 0 polls (relaxed, no cache maintenance), other waves wait at a
// barrier. Slot raise is RELEASE after a barrier that drains all waves'
// h stores. outbuf stores are nontemporal to keep L2 clean (cheap wbl2).
// Gate columns remapped lc -> (gate=(lc>>2)&3, j=4*(lc>>4)+(lc&3)): the 4
// gates of one (b,j) live in a 4-lane quad -> 3 shfl_xor combine; c/h state
// in registers of owner lanes (fl<4, fq<2). tanh(x)=2*sig(2x)-1.
constexpr int LWG  = 16;          // WGs per direction
constexpr int JW   = 32;          // hidden units per WG
constexpr int NTHR = 512;

__global__ __launch_bounds__(512)
void lstm_layer(const float* __restrict__ xgf, const float* __restrict__ xgb,
                const float* __restrict__ Wfull_f, const float* __restrict__ Wfull_b, int rowOff,
                const float* __restrict__ h0f, const float* __restrict__ c0f,
                const float* __restrict__ h0b, const float* __restrict__ c0b,
                const int* __restrict__ xtok,
                float* __restrict__ outbuf,       // [4096][1024], cols dir*512 + j
                u64* __restrict__ hbuf,           // [2 dirs][2 phases][128 jb][8 b] f16x4
                unsigned int* __restrict__ slots) // [2 dirs][16] one per WG
{
    __shared__ __align__(16) f16 Ws[16][128][32];  // [kc][local col][k in chunk] 128 KB
    __shared__ __align__(16) f16 hs[16][8][40];    // [kc][batch][32 f16 + pad]   10 KB
    __shared__ unsigned char toks[NB * SEQ];       // activity mask               4 KB

    const int bid = blockIdx.x;
    const int dir = bid >> 4;
    const int wg  = bid & 15;
    const int j0  = wg * JW;
    const int tid = threadIdx.x;
    const float* xg = dir ? xgb : xgf;
    const float* Wr = (dir ? Wfull_b : Wfull_f) + (size_t)rowOff * GD;  // h-part rows
    const float* h0 = dir ? h0b : h0f;
    const float* c0 = dir ? c0b : c0f;
    u64* hb = hbuf + dir * 2048;
    unsigned int* slot = slots + dir * LWG;

    const int lane = tid & 63;
    const int wv   = tid >> 6;            // wave 0..7 -> j block 4*wv..4*wv+3
    const int fl   = lane & 15;
    const int fq   = lane >> 4;
    const int gate = fl >> 2;             // 0=i 1=f 2=o 3=g
    const int jown = (fl & 3) + 4 * wv;   // 0..31
    const int gcol = gate * HD + j0 + jown;
    const bool owner = (fl < 4) && (fq < 2);
    const int srcBase = lane & 48;        // fq*16 (quad base for pack shfl)
    const int jb = wg * 8 + wv;           // this wave's u64 block in hb

    // ---- init c/h state in registers, publish h(0) ----
    float creg[4], hreg[4];
    {
        const float cv = owner ? c0[j0 + jown] : 0.f;
        const float hv = owner ? h0[j0 + jown] : 0.f;
        #pragma unroll
        for (int r = 0; r < 4; r++) { creg[r] = cv; hreg[r] = hv; }
        #pragma unroll
        for (int r = 0; r < 4; r++) {
            const float b0 = __shfl(hreg[r], srcBase | 0, 64);
            const float b1 = __shfl(hreg[r], srcBase | 1, 64);
            const float b2 = __shfl(hreg[r], srcBase | 2, 64);
            const float b3 = __shfl(hreg[r], srcBase | 3, 64);
            if (fl == 0 && fq < 2) {
                union { u64 u; f16 h[4]; } p;
                p.h[0]=(f16)b0; p.h[1]=(f16)b1; p.h[2]=(f16)b2; p.h[3]=(f16)b3;
                __hip_atomic_store(&hb[jb * 8 + fq * 4 + r], p.u,
                                   __ATOMIC_RELAXED, __HIP_MEMORY_SCOPE_AGENT);
            }
        }
    }

    // ---- preload W slice (k-major) + token mask into LDS, once ----
    for (int idx = tid; idx < 128 * 512; idx += NTHR) {
        const int k  = idx >> 7;          // 0..511
        const int lc = idx & 127;
        const int g  = (lc >> 2) & 3;
        const int jj = 4 * (lc >> 4) + (lc & 3);
        Ws[k >> 5][lc][k & 31] = (f16)Wr[(size_t)k * GD + g * HD + j0 + jj];
    }
    for (int idx = tid; idx < NB * SEQ; idx += NTHR)
        toks[idx] = (unsigned char)(xtok[idx] != 0);
    __syncthreads();   // drains h(0) stores of all waves + LDS preload
    if (tid == 0)
        __hip_atomic_store(&slot[wg], 1u, __ATOMIC_RELEASE, __HIP_MEMORY_SCOPE_AGENT);

    for (int s = 0; s < SEQ; s++) {
        const int t = dir ? (SEQ - 1 - s) : s;

        // prefetch x-gate contributions (independent of h; overlaps the wait)
        float xgv[4];
        if (fq < 2) {
            #pragma unroll
            for (int r = 0; r < 4; r++)
                xgv[r] = xg[(size_t)((fq*4 + r) * SEQ + t) * GD + gcol];
        }

        // wave 0 polls the 16 own-dir slots (one 64B line, relaxed)
        if (wv == 0) {
            const unsigned target = (unsigned)(s + 1);
            while (true) {
                const unsigned v = __hip_atomic_load(&slot[lane & 15],
                                   __ATOMIC_RELAXED, __HIP_MEMORY_SCOPE_AGENT);
                if (__all(v >= target)) break;
                __builtin_amdgcn_s_sleep(1);
            }
        }
        __syncthreads();                        // releases all waves

        // cooperative coalesced gather: 1024 u64 (8 KB), 2 per thread -> LDS
        {
            const u64* src = hb + (s & 1) * 1024;
            const int i0 = tid * 2;
            const u64 a = __hip_atomic_load(&src[i0],     __ATOMIC_RELAXED, __HIP_MEMORY_SCOPE_AGENT);
            const u64 b = __hip_atomic_load(&src[i0 + 1], __ATOMIC_RELAXED, __HIP_MEMORY_SCOPE_AGENT);
            const int jb0 = i0 >> 3,        bb0 = i0 & 7;
            const int jb1 = (i0 + 1) >> 3,  bb1 = (i0 + 1) & 7;
            *(u64*)&hs[jb0 >> 3][bb0][(jb0 & 7) * 4] = a;
            *(u64*)&hs[jb1 >> 3][bb1][(jb1 & 7) * 4] = b;
        }
        __syncthreads();                        // staging visible

        // recurrent matmul S = h @ Wslice (A rows = batches, dup rows 8..15)
        f32x4 acc0 = {0.f,0.f,0.f,0.f}, acc1 = {0.f,0.f,0.f,0.f};
        const int arow = fl & 7;
        const int lc   = wv * 16 + fl;
        #pragma unroll
        for (int kc = 0; kc < 16; kc += 2) {
            const f16x8 a0 = *(const f16x8*)&hs[kc    ][arow][fq*8];
            const f16x8 a1 = *(const f16x8*)&hs[kc + 1][arow][fq*8];
            const f16x8 b0 = *(const f16x8*)&Ws[kc    ][lc][fq*8];
            const f16x8 b1 = *(const f16x8*)&Ws[kc + 1][lc][fq*8];
            acc0 = __builtin_amdgcn_mfma_f32_16x16x32_f16(a0, b0, acc0, 0, 0, 0);
            acc1 = __builtin_amdgcn_mfma_f32_16x16x32_f16(a1, b1, acc1, 0, 0, 0);
        }

        // nonlinearity: gates 0..2 sigmoid, gate 3 tanh = 2*sig(2x)-1
        const bool isg = (gate == 3);
        float nl[4];
        #pragma unroll
        for (int r = 0; r < 4; r++) {
            float v = acc0[r] + acc1[r];
            if (fq < 2) v += xgv[r];
            const float a2 = isg ? (v + v) : v;
            const float sg = 1.f / (1.f + expf(-a2));
            nl[r] = isg ? (sg + sg - 1.f) : sg;
        }

        // butterfly across the gate dimension (quad lanes fl, fl^4, fl^8, fl^12)
        float outv[4];
        #pragma unroll
        for (int r = 0; r < 4; r++) {
            const float P = nl[r];
            const float Q = __shfl_xor(P, 4, 64);
            const float U = (gate & 1) ? Q : P;     // i (gates 0/1) or o (2/3)
            const float V = (gate & 1) ? P : Q;     // f or g
            const float U8 = __shfl_xor(U, 8, 64);
            const float V8 = __shfl_xor(V, 8, 64);
            const bool hi = (gate >= 2);
            const float gi = hi ? U8 : U;
            const float gf = hi ? V8 : V;
            const float go = hi ? U  : U8;
            const float gg = hi ? V  : V8;
            const float cn = gf * creg[r] + gi * gg;
            const float hn = go * tanhf(cn);
            const bool act = owner && (toks[(fq*4 + r) * SEQ + t] != 0);
            creg[r] = act ? cn : creg[r];
            hreg[r] = act ? hn : hreg[r];
            outv[r] = act ? hn : 0.f;
        }

        // publish h(s+1): each wave packs one 64B line of [jb][b] u64s
        u64* dst = hb + ((s + 1) & 1) * 1024;
        #pragma unroll
        for (int r = 0; r < 4; r++) {
            const float b0 = __shfl(hreg[r], srcBase | 0, 64);
            const float b1 = __shfl(hreg[r], srcBase | 1, 64);
            const float b2 = __shfl(hreg[r], srcBase | 2, 64);
            const float b3 = __shfl(hreg[r], srcBase | 3, 64);
            if (fl == 0 && fq < 2) {
                union { u64 u; f16 h[4]; } p;
                p.h[0]=(f16)b0; p.h[1]=(f16)b1; p.h[2]=(f16)b2; p.h[3]=(f16)b3;
                __hip_atomic_store(&dst[jb * 8 + fq * 4 + r], p.u,
                                   __ATOMIC_RELAXED, __HIP_MEMORY_SCOPE_AGENT);
            }
        }
        __syncthreads();   // all waves' h stores drained (vmcnt(0) at barrier)
        if (tid == 0)
            __hip_atomic_store(&slot[wg], (unsigned)(s + 2),
                               __ATOMIC_RELEASE, __HIP_MEMORY_SCOPE_AGENT);

        // sequence output (nontemporal: keeps L2 clean, off critical path)
        if (owner) {
            #pragma unroll
            for (int r = 0; r < 4; r++)
                __builtin_nontemporal_store(outv[r],
                    &outbuf[(size_t)((fq*4 + r) * SEQ + t) * 1024 + dir * 512 + j0 + jown]);
        }
    }
}

// ---------------- small kernels ------------------------------------------
__global__ void init_slots(unsigned int* s) { s[threadIdx.x] = 0u; }

__global__ __launch_bounds__(128)
void embed_kernel(const int* __restrict__ xtok, const float* __restrict__ emb,
                  float* __restrict__ dst) {
    const int r = blockIdx.x;
    const int tok = xtok[r];
    const float4* src = (const float4*)(emb + (size_t)tok * ED);
    float4* d = (float4*)(dst + (size_t)r * ED);
    d[threadIdx.x] = src[threadIdx.x];
}

__global__ __launch_bounds__(256)
void copycat_kernel(const float* __restrict__ enc, float* __restrict__ cat) {
    const int r = blockIdx.x;
    const int i = threadIdx.x * 4;
    *(float4*)&cat[(size_t)r * 2048 + i] = *(const float4*)&enc[(size_t)r * 1024 + i];
}

__global__ __launch_bounds__(256)
void softmax_kernel(float* __restrict__ sc, const int* __restrict__ xtok) {
    __shared__ float sm[4];
    const int r = blockIdx.x;          // b*512 + q
    const int b = r >> 9;
    const bool validq = xtok[r] != 0;
    float* row = sc + (size_t)r * 512;
    const int tid = threadIdx.x;
    float v0 = row[tid] * 0.03125f;
    float v1 = row[tid + 256] * 0.03125f;
    v0 = (xtok[(b << 9) + tid]       != 0) ? v0 : -3.402823466e38f;
    v1 = (xtok[(b << 9) + tid + 256] != 0) ? v1 : -3.402823466e38f;
    if (!validq) { v0 = 0.f; v1 = 0.f; }
    float m = wred_max(fmaxf(v0, v1));
    if ((tid & 63) == 0) sm[tid >> 6] = m;
    __syncthreads();
    m = fmaxf(fmaxf(sm[0], sm[1]), fmaxf(sm[2], sm[3]));
    const float e0 = expf(v0 - m), e1 = expf(v1 - m);
    float ssum = wred_sum(e0 + e1);
    __syncthreads();
    if ((tid & 63) == 0) sm[tid >> 6] = ssum;
    __syncthreads();
    ssum = (sm[0] + sm[1]) + (sm[2] + sm[3]);
    const float inv = 1.f / ssum;
    row[tid]       = validq ? e0 * inv : 0.f;
    row[tid + 256] = validq ? e1 * inv : 0.f;
}

__global__ __launch_bounds__(256)
void ln1_kernel(const float* __restrict__ enc, const float* __restrict__ ao,
                const float* __restrict__ g, const float* __restrict__ be,
                const int* __restrict__ xtok, float* __restrict__ out) {
    __shared__ float sm[8];
    const int r = blockIdx.x;
    const bool valid = xtok[r] != 0;
    const float* er = enc + (size_t)r * 1024;
    const float* ar = ao + (size_t)r * 1024;
    float* orow = out + (size_t)r * 1024;
    const int tid = threadIdx.x;
    float v[4]; float s = 0.f, ss = 0.f;
    #pragma unroll
    for (int u = 0; u < 4; u++) {
        const int d = tid + u * 256;
        const float val = er[d] + tanhf(ar[d]);
        v[u] = val; s += val; ss += val * val;
    }
    s = wred_sum(s); ss = wred_sum(ss);
    if ((tid & 63) == 0) { sm[tid >> 6] = s; sm[4 + (tid >> 6)] = ss; }
    __syncthreads();
    s  = (sm[0] + sm[1]) + (sm[2] + sm[3]);
    ss = (sm[4] + sm[5]) + (sm[6] + sm[7]);
    const float mean = s * (1.f / 1024.f);
    const float var = ss * (1.f / 1024.f) - mean * mean;
    const float rstd = rsqrtf(var + 1e-5f);
    #pragma unroll
    for (int u = 0; u < 4; u++) {
        const int d = tid + u * 256;
        const float y = (v[u] - mean) * rstd * g[d] + be[d];
        orow[d] = valid ? y : 0.f;
    }
}

__global__ __launch_bounds__(256)
void ln2_kernel(const float* __restrict__ hp, const float* __restrict__ g,
                const float* __restrict__ be, float* __restrict__ out) {
    __shared__ float sm[8];
    const int r = blockIdx.x;
    const float* src = hp + (size_t)r * 512;
    float* orow = out + (size_t)r * 512;
    const int tid = threadIdx.x;
    float v[2]; float s = 0.f, ss = 0.f;
    #pragma unroll
    for (int u = 0; u < 2; u++) {
        const int d = tid + u * 256;
        const float xx = src[d];
        const float val = 0.5f * xx * (1.f + erff(xx * 0.7071067811865475f)); // exact gelu
        v[u] = val; s += val; ss += val * val;
    }
    s = wred_sum(s); ss = wred_sum(ss);
    if ((tid & 63) == 0) { sm[tid >> 6] = s; sm[4 + (tid >> 6)] = ss; }
    __syncthreads();
    s  = (sm[0] + sm[1]) + (sm[2] + sm[3]);
    ss = (sm[4] + sm[5]) + (sm[6] + sm[7]);
    const float mean = s * (1.f / 512.f);
    const float var = ss * (1.f / 512.f) - mean * mean;
    const float rstd = rsqrtf(var + 1e-5f);
    #pragma unroll
    for (int u = 0; u < 2; u++) {
        const int d = tid + u * 256;
        orow[d] = (v[u] - mean) * rstd * g[d] + be[d];
    }
}

// ---------------- host launcher ------------------------------------------
extern "C" void kernel_launch(void* const* d_in, const int* in_sizes, int n_in,
                              void* d_out, int out_size, void* d_ws, size_t ws_size,
                              hipStream_t stream) {
    const int*   x    = (const int*)  d_in[0];
    const float* emb  = (const float*)d_in[1];
    const float* Wf0  = (const float*)d_in[2];
    const float* bf0  = (const float*)d_in[3];
    const float* Wb0  = (const float*)d_in[4];
    const float* bb0  = (const float*)d_in[5];
    const float* Wf1  = (const float*)d_in[6];
    const float* bf1  = (const float*)d_in[7];
    const float* Wb1  = (const float*)d_in[8];
    const float* bb1  = (const float*)d_in[9];
    const float* h0f  = (const float*)d_in[10];
    const float* c0f  = (const float*)d_in[11];
    const float* h0b  = (const float*)d_in[12];
    const float* c0b  = (const float*)d_in[13];
    const float* Wq   = (const float*)d_in[14];
    const float* bq   = (const float*)d_in[15];
    const float* Wao  = (const float*)d_in[16];
    const float* bao  = (const float*)d_in[17];
    const float* ln1g = (const float*)d_in[18];
    const float* ln1b = (const float*)d_in[19];
    const float* Wh   = (const float*)d_in[20];
    const float* bh   = (const float*)d_in[21];
    const float* ln2g = (const float*)d_in[22];
    const float* ln2b = (const float*)d_in[23];
    const float* Wp   = (const float*)d_in[24];
    const float* obia = (const float*)d_in[25];
    float* out = (float*)d_out;
    float* ws  = (float*)d_ws;

    // Arena inside d_out (524 MB; intermediates ~200 MB, fully overwritten by
    // the final GEMM which only reads head (in d_ws) + Wp + out_bias).
    float* emb_seq = out;                                  // 2M floats
    float* xgf  = out + (size_t)2 * 1024 * 1024;           // 8M (reused layer0/1)
    float* xgb  = xgf + (size_t)8 * 1024 * 1024;           // 8M
    float* lin1 = xgb + (size_t)8 * 1024 * 1024;           // 4M
    float* enc  = lin1 + (size_t)4 * 1024 * 1024;          // 4M
    float* qry  = enc  + (size_t)4 * 1024 * 1024;          // 4M
    float* att  = qry  + (size_t)4 * 1024 * 1024;          // 2M
    float* cat  = att  + (size_t)2 * 1024 * 1024;          // 8M
    float* aop  = cat  + (size_t)8 * 1024 * 1024;          // 4M
    float* refd = aop  + (size_t)4 * 1024 * 1024;          // 4M
    float* hpre = refd + (size_t)4 * 1024 * 1024;          // 2M -> 50M total

    float* head = ws;                                      // 2M floats
    u64*   hbuf = (u64*)(ws + (size_t)2 * 1024 * 1024);    // 4096 u64 = 32 KB
    unsigned int* slots = (unsigned int*)(hbuf + 4096);    // 64 uints (2 layers)

    init_slots<<<1, 64, 0, stream>>>(slots);
    embed_kernel<<<NROWS, 128, 0, stream>>>(x, emb, emb_seq);
    // layer 0 x-gates (bias fused)
    gemm_f16<0><<<dim3(GD/128, NROWS/128, 1), 256, 0, stream>>>(emb_seq, ED, 0, Wf0, GD, 0, bf0, xgf, GD, 0, ED);
    gemm_f16<0><<<dim3(GD/128, NROWS/128, 1), 256, 0, stream>>>(emb_seq, ED, 0, Wb0, GD, 0, bb0, xgb, GD, 0, ED);
    lstm_layer<<<32, 512, 0, stream>>>(xgf, xgb, Wf0, Wb0, ED, h0f, c0f, h0b, c0b, x, lin1, hbuf, slots);
    // layer 1 x-gates (K = 2H = 1024)
    gemm_f16<0><<<dim3(GD/128, NROWS/128, 1), 256, 0, stream>>>(lin1, 1024, 0, Wf1, GD, 0, bf1, xgf, GD, 0, 1024);
    gemm_f16<0><<<dim3(GD/128, NROWS/128, 1), 256, 0, stream>>>(lin1, 1024, 0, Wb1, GD, 0, bb1, xgb, GD, 0, 1024);
    lstm_layer<<<32, 512, 0, stream>>>(xgf, xgb, Wf1, Wb1, 1024, h0f + 512, c0f + 512, h0b + 512, c0b + 512, x, enc, hbuf, slots + 32);
    // attention
    gemm_f16<0><<<dim3(1024/128, NROWS/128, 1), 256, 0, stream>>>(enc, 1024, 0, Wq, 1024, 0, bq, qry, 1024, 0, 1024);
    gemm_f16<1><<<dim3(4, 4, 8), 256, 0, stream>>>(qry, 1024, (long long)512*1024, enc, 1024, (long long)512*1024, nullptr, att, 512, (long long)512*512, 1024);
    softmax_kernel<<<NROWS, 256, 0, stream>>>(att, x);
    copycat_kernel<<<NROWS, 256, 0, stream>>>(enc, cat);
    gemm_f16<0><<<dim3(8, 4, 8), 256, 0, stream>>>(att, 512, (long long)512*512, enc, 1024, (long long)512*1024, nullptr, cat + 1024, 2048, (long long)512*2048, 512);
    // refine + LN1
    gemm_f16<0><<<dim3(1024/128, NROWS/128, 1), 256, 0, stream>>>(cat, 2048, 0, Wao, 1024, 0, bao, aop, 1024, 0, 2048);
    ln1_kernel<<<NROWS, 256, 0, stream>>>(enc, aop, ln1g, ln1b, x, refd);
    // head + LN2
    gemm_f16<0><<<dim3(512/128, NROWS/128, 1), 256, 0, stream>>>(refd, 1024, 0, Wh, 512, 0, bh, hpre, 512, 0, 1024);
    ln2_kernel<<<NROWS, 256, 0, stream>>>(hpre, ln2g, ln2b, head);
    // vocab projection (writes every element of d_out)
    gemm_f16<0><<<dim3(32000/128, NROWS/128, 1), 256, 0, stream>>>(head, 512, 0, Wp, 32000, 0, obia, out, 32000, 0, 512);
}